// Round 2
// baseline (528.386 us; speedup 1.0000x reference)
//
#include <hip/hip_runtime.h>

// DotProcessorBlock: feat = x*w + b (B=4096, N=256); out[b, :] = first
// n(n+1)/2 = 32896 row-major entries of feat ⊗ feat.
// 32896 = 128 full rows of 256 + 128 entries of row 128.
// Pure HBM-write-bound: 539 MB out vs 4 MB in.
//
// R1/R2: nontemporal stores. Output is write-once, 539 MB (2x the 256 MB
// Infinity Cache) -> regular stores write-allocate and thrash L2/L3,
// measured ~2.9 TB/s vs the 6.3 TB/s the harness fill reaches. `nt`
// stores stream past the caches. (R1 bench was an infra failure —
// container acquisition — so this is an unchanged resubmit.)

#define NFEAT 256
#define NOUT  32896   // 256*257/2

typedef float f32x4 __attribute__((ext_vector_type(4)));

__global__ __launch_bounds__(256) void dot_outer_kernel(
    const float* __restrict__ x,
    const float* __restrict__ w,
    const float* __restrict__ bias,
    float* __restrict__ out)
{
    __shared__ float feat[NFEAT];
    const int b = blockIdx.x;
    const int t = threadIdx.x;

    // feat = x*w + b  (coalesced: lane t loads element t)
    feat[t] = x[(size_t)b * NFEAT + t] * w[t] + bias[t];
    __syncthreads();

    const f32x4* feat4 = (const f32x4*)feat;
    f32x4* out4 = (f32x4*)(out + (size_t)b * NOUT);

    // Loop-invariant: lane t always multiplies against feat4[t & 63]
    // (within a wave, lanes 0..63 cover the full 256-feature row).
    const f32x4 fj = feat4[t & 63];

    // Main body: 32 iterations x 256 threads = 8192 float4 stores
    // covering rows i = 0..127 (each 64-lane wave handles one full row:
    // feat[i] is a wave-uniform LDS broadcast).
    #pragma unroll
    for (int iter = 0; iter < 32; ++iter) {
        const int idx = iter * 256 + t;      // float4 index within batch
        const float fi = feat[idx >> 6];     // row 0..127, wave-uniform
        f32x4 v;
        v.x = fi * fj.x;
        v.y = fi * fj.y;
        v.z = fi * fj.z;
        v.w = fi * fj.w;
        __builtin_nontemporal_store(v, &out4[idx]);
    }

    // Tail: row 128, cols 0..127 -> 32 float4 stores
    if (t < 32) {
        const float fi = feat[128];
        const f32x4 fjt = feat4[t];
        f32x4 v;
        v.x = fi * fjt.x;
        v.y = fi * fjt.y;
        v.z = fi * fjt.z;
        v.w = fi * fjt.w;
        __builtin_nontemporal_store(v, &out4[8192 + t]);
    }
}

extern "C" void kernel_launch(void* const* d_in, const int* in_sizes, int n_in,
                              void* d_out, int out_size, void* d_ws, size_t ws_size,
                              hipStream_t stream) {
    const float* x    = (const float*)d_in[0];
    const float* w    = (const float*)d_in[1];
    const float* bias = (const float*)d_in[2];
    float* out = (float*)d_out;

    const int B = in_sizes[0] / NFEAT;   // 4096
    dot_outer_kernel<<<B, 256, 0, stream>>>(x, w, bias, out);
}